// Round 4
// baseline (189.570 us; speedup 1.0000x reference)
//
#include <hip/hip_runtime.h>
#include <hip/hip_bf16.h>

typedef __attribute__((ext_vector_type(8))) short bf16x8_t;
typedef __attribute__((ext_vector_type(4))) float f32x4_t;

#define B_   4
#define C_   512
#define N_   4096
#define NQK_ 128   // Q(64) | K(64) channel-concat width
#define NT_  128   // N_/32 j-tiles
#define NP_  64    // 2-tile barrier periods

typedef unsigned short ushort_t;

__device__ __forceinline__ ushort_t f2bf(float f) {
    union { float f; unsigned int u; } un; un.f = f;
    unsigned int r = un.u + 0x7FFF + ((un.u >> 16) & 1); // RNE
    return (ushort_t)(r >> 16);
}

__device__ __forceinline__ bf16x8_t load8(const ushort_t* p) {
    return *reinterpret_cast<const bf16x8_t*>(p);
}

__device__ __forceinline__ unsigned pk2(float lo, float hi) {
    return (unsigned)f2bf(lo) | ((unsigned)f2bf(hi) << 16);
}

// async global->LDS, 16B per lane; dest is wave-uniform base (+ lane*16 in HW)
#define GLL16(g, l) __builtin_amdgcn_global_load_lds( \
    (const __attribute__((address_space(1))) unsigned int*)(g), \
    (__attribute__((address_space(3))) unsigned int*)(l), 16, 0, 0)

// ------------------------------------------- transpose+cast x -> Xt[b][n][c]
// z==4: weight/bias cast (folded-in former cast_w kernel)
__global__ __launch_bounds__(256) void transpose_cast_x(
        const float* __restrict__ x, ushort_t* __restrict__ Xt,
        const float* __restrict__ w1, const float* __restrict__ b1,
        const float* __restrict__ w2, const float* __restrict__ b2,
        const float* __restrict__ w3, const float* __restrict__ b3,
        ushort_t* __restrict__ Wb, float* __restrict__ bias_all) {
    if (blockIdx.z == 4) {
        int bid = blockIdx.y * 64 + blockIdx.x;          // 0..511
        int t0 = bid * 256 + threadIdx.x;                // 0..131071
        for (int idx = t0; idx < 640 * 512 + 640; idx += 131072) {
            if (idx < 64 * 512) {
                Wb[idx] = f2bf(w1[idx]);
            } else if (idx < 128 * 512) {
                Wb[idx] = f2bf(w2[idx - 64 * 512]);
            } else if (idx < 640 * 512) {
                Wb[idx] = f2bf(w3[idx - 128 * 512]);
            } else {
                int i = idx - 640 * 512;
                bias_all[i] = (i < 64) ? b1[i] : (i < 128 ? b2[i - 64] : b3[i - 128]);
            }
        }
        return;
    }
    int b = blockIdx.z, c0 = blockIdx.y * 64, n0 = blockIdx.x * 64;
    int tid = threadIdx.x;
    __shared__ float t[64][65];
    const float* xb = x + ((size_t)b * C_ + c0) * N_ + n0;
    // load phase: lane covers c-row (tid>>4), 4 consecutive n (tid&15)*4
    #pragma unroll
    for (int it = 0; it < 4; ++it) {
        int cl = it * 16 + (tid >> 4), nq = (tid & 15) * 4;
        const float4 v = *reinterpret_cast<const float4*>(xb + (size_t)cl * N_ + nq);
        t[cl][nq + 0] = v.x; t[cl][nq + 1] = v.y;
        t[cl][nq + 2] = v.z; t[cl][nq + 3] = v.w;
    }
    __syncthreads();
    // store phase: lane covers n-row (tid>>4), 4 consecutive c (tid&15)*4
    #pragma unroll
    for (int it = 0; it < 4; ++it) {
        int nl = it * 16 + (tid >> 4), cq = (tid & 15) * 4;
        ushort4 o;
        o.x = f2bf(t[cq + 0][nl]); o.y = f2bf(t[cq + 1][nl]);
        o.z = f2bf(t[cq + 2][nl]); o.w = f2bf(t[cq + 3][nl]);
        *reinterpret_cast<ushort4*>(&Xt[((size_t)b * N_ + n0 + nl) * C_ + c0 + cq]) = o;
    }
}

// ---------------------------------------------------- fused QK + V GEMMs
// grid (32, 20). Register double-buffered K-loop (round 14, kept).
__global__ __launch_bounds__(256) void gemm_qkv_kernel(
        const ushort_t* __restrict__ Xt, const ushort_t* __restrict__ Wb,
        const float* __restrict__ bias, ushort_t* __restrict__ QK,
        ushort_t* __restrict__ V) {
    int sel = blockIdx.y;
    int n0 = blockIdx.x * 128;
    int tid = threadIdx.x;
    int l = tid & 63, w = tid >> 6;
    int wr = w >> 1, wc = w & 1;
    int lr = l & 15, lg = l >> 4;
    if (sel < 4) {
        int b = sel;
        const ushort_t* Xb = Xt + (size_t)b * N_ * C_;
        const ushort_t* ap = Xb + (size_t)(n0 + wr * 64 + lr) * 512 + lg * 8;
        const ushort_t* bp = Wb + (size_t)(wc * 64 + lr) * 512 + lg * 8;
        f32x4_t acc[4][4] = {};
        bf16x8_t a[4], bb[4];
        #pragma unroll
        for (int f = 0; f < 4; ++f) {
            a[f]  = load8(ap + (size_t)f * 16 * 512);
            bb[f] = load8(bp + (size_t)f * 16 * 512);
        }
        for (int kk = 0; kk < 512; kk += 32) {
            bf16x8_t na[4], nbb[4];
            if (kk + 32 < 512) {
                #pragma unroll
                for (int f = 0; f < 4; ++f) {
                    na[f]  = load8(ap + (size_t)f * 16 * 512 + kk + 32);
                    nbb[f] = load8(bp + (size_t)f * 16 * 512 + kk + 32);
                }
            }
            #pragma unroll
            for (int fi = 0; fi < 4; ++fi)
                #pragma unroll
                for (int fj = 0; fj < 4; ++fj)
                    acc[fi][fj] = __builtin_amdgcn_mfma_f32_16x16x32_bf16(
                        a[fi], bb[fj], acc[fi][fj], 0, 0, 0);
            if (kk + 32 < 512) {
                #pragma unroll
                for (int f = 0; f < 4; ++f) { a[f] = na[f]; bb[f] = nbb[f]; }
            }
        }
        #pragma unroll
        for (int fi = 0; fi < 4; ++fi)
            #pragma unroll
            for (int fj = 0; fj < 4; ++fj)
                #pragma unroll
                for (int r = 0; r < 4; ++r) {
                    int n = n0 + wr * 64 + fi * 16 + lg * 4 + r;
                    int col = wc * 64 + fj * 16 + lr;
                    QK[((size_t)b * N_ + n) * NQK_ + col] = f2bf(acc[fi][fj][r] + bias[col]);
                }
    } else {
        int m0 = ((sel - 4) & 3) * 128;
        int b  = (sel - 4) >> 2;
        const ushort_t* Xb = Xt + (size_t)b * N_ * C_;
        const ushort_t* Wv = Wb + 128 * 512;
        const ushort_t* ap = Wv + (size_t)(m0 + wr * 64 + lr) * 512 + lg * 8;
        const ushort_t* bp = Xb + (size_t)(n0 + wc * 64 + lr) * 512 + lg * 8;
        f32x4_t acc[4][4] = {};
        bf16x8_t a[4], bb[4];
        #pragma unroll
        for (int f = 0; f < 4; ++f) {
            a[f]  = load8(ap + (size_t)f * 16 * 512);
            bb[f] = load8(bp + (size_t)f * 16 * 512);
        }
        for (int kk = 0; kk < 512; kk += 32) {
            bf16x8_t na[4], nbb[4];
            if (kk + 32 < 512) {
                #pragma unroll
                for (int f = 0; f < 4; ++f) {
                    na[f]  = load8(ap + (size_t)f * 16 * 512 + kk + 32);
                    nbb[f] = load8(bp + (size_t)f * 16 * 512 + kk + 32);
                }
            }
            #pragma unroll
            for (int fi = 0; fi < 4; ++fi)
                #pragma unroll
                for (int fj = 0; fj < 4; ++fj)
                    acc[fi][fj] = __builtin_amdgcn_mfma_f32_16x16x32_bf16(
                        a[fi], bb[fj], acc[fi][fj], 0, 0, 0);
            if (kk + 32 < 512) {
                #pragma unroll
                for (int f = 0; f < 4; ++f) { a[f] = na[f]; bb[f] = nbb[f]; }
            }
        }
        #pragma unroll
        for (int fi = 0; fi < 4; ++fi)
            #pragma unroll
            for (int fj = 0; fj < 4; ++fj)
                #pragma unroll
                for (int r = 0; r < 4; ++r) {
                    int d = m0 + wr * 64 + fi * 16 + lg * 4 + r;
                    int n = n0 + wc * 64 + fj * 16 + lr;
                    V[((size_t)b * C_ + d) * N_ + n] = f2bf(acc[fi][fj][r] + bias[128 + d]);
                }
    }
}

// ---------------------------------------------------- fused flash attention
// grid 256 x 768thr (12 waves). Round 22: V in registers with MANUALLY
// COUNTED vmcnt via volatile asm. Rounds 1-2 failed because visible loads
// let the compiler own waitcnt placement: at the divergent S/PV join its
// merged counter state degenerates to ~vmcnt(0) at first use (round 1), and
// same-block loads are latency-exposed (round 2). Here the loads are opaque
// volatile asm (compiler inserts NO waits; PV waves have no other VMEM, so
// per-wave vmcnt counting is exact). Two banks E/O (even/odd tiles, 32
// VGPRs): wait vmcnt(4) -> consume E -> reissue E(tile 2p) -> wait vmcnt(4)
// -> consume O -> reissue O(tile 2p+1); each load in flight >= half a period
// (~2000cyc) before its wait. sched_barrier(0) after each wait (rule #18:
// MFMAs hoist past inline-asm waits). Removes Vl (LDS 140.8->42.3KB),
// ~128KB/period LDS traffic, PVSTEP's lgkm(0) WAR serialization, and the
// vmcnt(4) pacing. V addressing identical to rounds 1-2 (numerics verified).
__global__ __launch_bounds__(768, 3) void attn_kernel(
        const ushort_t* __restrict__ QK, const ushort_t* __restrict__ V,
        const float* __restrict__ feat, const float* __restrict__ gamma,
        float* __restrict__ out) {
    __shared__ ushort_t Kl3[3][4096];                // K 2-tile bufs x3, XOR-swizzled
    __shared__ ushort_t Pl[2][4096];                 // P banks (2 tiles each)
    __shared__ float    fl[2][128];                  // per-q rescale, [bank][tt*64+q]
    __shared__ __align__(16) unsigned flagl[2][8];   // [bank][tt*4+qt]
    __shared__ float    invl[64];                    // final 1/ssum per q

    int bid = blockIdx.x;
    int lid = (bid & 7) * 32 + (bid >> 3);  // XCD-contiguous: one batch per 2 XCDs
    int b  = lid >> 6;
    int i0 = (lid & 63) * 64;

    int tid = threadIdx.x;
    int l = tid & 63, w = tid >> 6;
    int lr = l & 15, lg = l >> 4;
    int ds = (w >= 4) ? (w - 4) : 0;        // 0..7, 64-channel slice

    const ushort_t* QKb = QK + (size_t)b * N_ * NQK_;
    const ushort_t* Vb  = V  + (size_t)b * C_ * N_;

    // ---- S-wave persistent state
    bf16x8_t qf0 = {}, qf1 = {};
    const ushort_t* ksrc = nullptr;
    float mreg = -1e30f, ssum = 0.0f;       // ssum group-partial (reduced at end)
    const int maskk = (lr & 7) << 4;  // K read swizzle
    if (w < 4) {
        qf0 = load8(QKb + (size_t)(i0 + w * 16 + lr) * NQK_ + lg * 8);
        qf1 = load8(QKb + (size_t)(i0 + w * 16 + lr) * NQK_ + 32 + lg * 8);
        int p = w * 1024 + l * 16;
        int o = p ^ (((p >> 7) & 7) << 4);
        ksrc = QKb + (size_t)(o >> 7) * NQK_ + 64 + ((o & 127) >> 1);
    }

    // ---- PV-wave persistent state: V frags via opaque asm loads.
    // lane l A-frag: row = ds*64 + dt*16 + lr, cols = tile*32 + lg*8.
    const ushort_t* vgE = Vb + (size_t)(ds * 64 + lr) * N_ + lg * 8;       // even tiles
    const ushort_t* vgO = vgE + 32;                                        // odd tiles
    bf16x8_t E0, E1, E2, E3, O0, O1, O2, O3;
    f32x4_t acc[4][4] = {};

// opaque 16B global load: compiler does not model it as a load -> no
// auto-waitcnt; we count vmcnt manually (PV waves execute no other VMEM
// until the epilogue, by which point all are drained).
#define VLOAD(D, P) asm volatile("global_load_dwordx4 %0, %1, off" \
        : "=v"(D) : "v"(P) : "memory")
#define VFETCH4(A0, A1, A2, A3, P)                   \
    VLOAD(A0, (P));                                  \
    VLOAD(A1, (P) + (size_t)16 * N_);                \
    VLOAD(A2, (P) + (size_t)32 * N_);                \
    VLOAD(A3, (P) + (size_t)48 * N_);

    // prologue: S stages K periods 0,1 (buf0,buf1), waits buf0 (buf1 in
    // flight). PV issues tiles 0 (E) and 1 (O): 8 loads outstanding.
    if (w < 4) {
        GLL16(ksrc,                         &Kl3[0][w * 512]);
        GLL16(ksrc + (size_t)1 * 32 * NQK_, &Kl3[0][2048 + w * 512]);
        GLL16(ksrc + (size_t)2 * 32 * NQK_, &Kl3[1][w * 512]);
        GLL16(ksrc + (size_t)3 * 32 * NQK_, &Kl3[1][2048 + w * 512]);
        asm volatile("s_waitcnt vmcnt(2)" ::: "memory");
    } else {
        VFETCH4(E0, E1, E2, E3, vgE)
        vgE += 64;
        VFETCH4(O0, O1, O2, O3, vgO)
        vgO += 64;
    }
    asm volatile("" ::: "memory");
    __builtin_amdgcn_s_barrier();
    asm volatile("" ::: "memory");

#define SOFTMAX_WRITE(SO0, SO1, PM, TT)                                        \
    {                                                                          \
        float pmax = fmaxf(fmaxf(fmaxf(SO0[0],SO0[1]), fmaxf(SO0[2],SO0[3])),  \
                           fmaxf(fmaxf(SO1[0],SO1[1]), fmaxf(SO1[2],SO1[3]))); \
        pmax = fmaxf(pmax, __shfl_xor(pmax, 16));                              \
        pmax = fmaxf(pmax, __shfl_xor(pmax, 32));                              \
        bool anyneed = __any(pmax > mreg + 8.0f);                              \
        if (anyneed) {                                                         \
            float mn = fmaxf(mreg, pmax);                                      \
            float f_ = __expf(mreg - mn);                                      \
            mreg = mn; ssum *= f_;                                             \
            if (lg == 0) fl[PM][(TT) * 64 + w * 16 + lr] = f_;                 \
        }                                                                      \
        if (l == 0) flagl[PM][(TT) * 4 + w] = anyneed ? 1u : 0u;               \
        float e00 = __expf(SO0[0]-mreg), e01 = __expf(SO0[1]-mreg);            \
        float e02 = __expf(SO0[2]-mreg), e03 = __expf(SO0[3]-mreg);            \
        float e10 = __expf(SO1[0]-mreg), e11 = __expf(SO1[1]-mreg);            \
        float e12 = __expf(SO1[2]-mreg), e13 = __expf(SO1[3]-mreg);            \
        ssum += (e00+e01)+(e02+e03)+(e10+e11)+(e12+e13);  /* group-partial */  \
        int lt = lr + (lg >> 1) * 16;                                          \
        uint2 w0v; w0v.x = pk2(e00, e01); w0v.y = pk2(e02, e03);               \
        uint2 w1v; w1v.x = pk2(e10, e11); w1v.y = pk2(e12, e13);               \
        *reinterpret_cast<uint2*>(&Pl[PM][(TT)*2048 + w*512 + lt*8 + (lg&1)*4]) = w0v; \
        *reinterpret_cast<uint2*>(&Pl[PM][(TT)*2048 + w*512 + (lt+32)*8 + (lg&1)*4]) = w1v; \
    }

// PV: consume one tile (P bank PB, slot TT) with V fragments V0..V3 already
// resident (landed under the preceding manual vmcnt wait). Rescale by the
// deferred-max factors, then 16 MFMAs with lazy pa loads from Pl.
#define PVSTEP_R(PB, TT, V0, V1, V2, V3)                                       \
    {                                                                          \
        uint4 fv = *reinterpret_cast<const uint4*>(&flagl[PB][(TT) * 4]);      \
        if ((int)__builtin_amdgcn_readfirstlane(fv.x)) {                       \
            float fq = fl[PB][(TT) * 64 + lr];                                 \
            _Pragma("unroll") for (int dt = 0; dt < 4; ++dt) acc[dt][0] *= fq; \
        }                                                                      \
        if ((int)__builtin_amdgcn_readfirstlane(fv.y)) {                       \
            float fq = fl[PB][(TT) * 64 + 16 + lr];                            \
            _Pragma("unroll") for (int dt = 0; dt < 4; ++dt) acc[dt][1] *= fq; \
        }                                                                      \
        if ((int)__builtin_amdgcn_readfirstlane(fv.z)) {                       \
            float fq = fl[PB][(TT) * 64 + 32 + lr];                            \
            _Pragma("unroll") for (int dt = 0; dt < 4; ++dt) acc[dt][2] *= fq; \
        }                                                                      \
        if ((int)__builtin_amdgcn_readfirstlane(fv.w)) {                       \
            float fq = fl[PB][(TT) * 64 + 48 + lr];                            \
            _Pragma("unroll") for (int dt = 0; dt < 4; ++dt) acc[dt][3] *= fq; \
        }                                                                      \
        __builtin_amdgcn_s_setprio(1);                                         \
        _Pragma("unroll") for (int qt = 0; qt < 4; ++qt) {                     \
            bf16x8_t pa = load8(&Pl[PB][(TT) * 2048 + qt * 512 + l * 8]);      \
            acc[0][qt] = __builtin_amdgcn_mfma_f32_16x16x32_bf16(              \
                V0, pa, acc[0][qt], 0, 0, 0);                                  \
            acc[1][qt] = __builtin_amdgcn_mfma_f32_16x16x32_bf16(              \
                V1, pa, acc[1][qt], 0, 0, 0);                                  \
            acc[2][qt] = __builtin_amdgcn_mfma_f32_16x16x32_bf16(              \
                V2, pa, acc[2][qt], 0, 0, 0);                                  \
            acc[3][qt] = __builtin_amdgcn_mfma_f32_16x16x32_bf16(              \
                V3, pa, acc[3][qt], 0, 0, 0);                                  \
        }                                                                      \
        __builtin_amdgcn_s_setprio(0);                                         \
    }

    for (int p = 0; p < NP_; ++p) {
        int pb = p % 3;
        if (w < 4) {
            // stage K for period p+2
            if (p + 2 < NP_) {
                int pn = pb + 2; if (pn >= 3) pn -= 3;
                GLL16(ksrc + (size_t)(2 * p + 4) * 32 * NQK_, &Kl3[pn][w * 512]);
                GLL16(ksrc + (size_t)(2 * p + 5) * 32 * NQK_, &Kl3[pn][2048 + w * 512]);
            }
            const ushort_t* kbp = &Kl3[pb][0];
            // tile 2p
            bf16x8_t kf00, kf01, kf10, kf11;
            { int o = (lr << 7) + (lg << 4);              kf00 = load8(kbp + ((o ^ maskk) >> 1)); }
            { int o = (lr << 7) + 64 + (lg << 4);         kf01 = load8(kbp + ((o ^ maskk) >> 1)); }
            { int o = ((16 + lr) << 7) + (lg << 4);       kf10 = load8(kbp + ((o ^ maskk) >> 1)); }
            { int o = ((16 + lr) << 7) + 64 + (lg << 4);  kf11 = load8(kbp + ((o ^ maskk) >> 1)); }
            f32x4_t s00 = {0.f,0.f,0.f,0.f}, s01 = {0.f,0.f,0.f,0.f};
            s00 = __builtin_amdgcn_mfma_f32_16x16x32_bf16(kf00, qf0, s00, 0,0,0);
            s00 = __builtin_amdgcn_mfma_f32_16x16x32_bf16(kf01, qf1, s00, 0,0,0);
            s01 = __builtin_amdgcn_mfma_f32_16x16x32_bf16(kf10, qf0, s01, 0,0,0);
            s01 = __builtin_amdgcn_mfma_f32_16x16x32_bf16(kf11, qf1, s01, 0,0,0);
            // tile 2p+1
            const ushort_t* kbq = kbp + 2048;
            bf16x8_t kg00, kg01, kg10, kg11;
            { int o = (lr << 7) + (lg << 4);              kg00 = load8(kbq + ((o ^ maskk) >> 1)); }
            { int o = (lr << 7) + 64 + (lg << 4);         kg01 = load8(kbq + ((o ^ maskk) >> 1)); }
            { int o = ((16 + lr) << 7) + (lg << 4);       kg10 = load8(kbq + ((o ^ maskk) >> 1)); }
            { int o = ((16 + lr) << 7) + 64 + (lg << 4);  kg11 = load8(kbq + ((o ^ maskk) >> 1)); }
            f32x4_t s10 = {0.f,0.f,0.f,0.f}, s11 = {0.f,0.f,0.f,0.f};
            s10 = __builtin_amdgcn_mfma_f32_16x16x32_bf16(kg00, qf0, s10, 0,0,0);
            s10 = __builtin_amdgcn_mfma_f32_16x16x32_bf16(kg01, qf1, s10, 0,0,0);
            s11 = __builtin_amdgcn_mfma_f32_16x16x32_bf16(kg10, qf0, s11, 0,0,0);
            s11 = __builtin_amdgcn_mfma_f32_16x16x32_bf16(kg11, qf1, s11, 0,0,0);
            // softmax 2p (while 2p+1's MFMAs retire), then 2p+1
            int bank = p & 1;
            SOFTMAX_WRITE(s00, s01, bank, 0)
            SOFTMAX_WRITE(s10, s11, bank, 1)
            asm volatile("s_waitcnt vmcnt(2) lgkmcnt(0)" ::: "memory");
        } else {
            if (p >= 1) {
                int pbk = (p - 1) & 1;
                // E holds tile 2p-2 (landed when <=4 loads outstanding),
                // O holds tile 2p-1 (in flight).
                asm volatile("s_waitcnt vmcnt(4)" ::: "memory");
                __builtin_amdgcn_sched_barrier(0);
                PVSTEP_R(pbk, 0, E0, E1, E2, E3)
                VFETCH4(E0, E1, E2, E3, vgE)   // tile 2p; outstanding: O(4)+E(4)
                vgE += 64;
                asm volatile("s_waitcnt vmcnt(4)" ::: "memory");
                __builtin_amdgcn_sched_barrier(0);
                PVSTEP_R(pbk, 1, O0, O1, O2, O3)
                VFETCH4(O0, O1, O2, O3, vgO)   // tile 2p+1; outstanding: E(4)+O(4)
                vgO += 64;
            }
        }
        asm volatile("" ::: "memory");
        __builtin_amdgcn_s_barrier();
        asm volatile("" ::: "memory");
    }

    // tail A: S reduces group-partial ssum, publishes invl.
    // PV's loads for tiles 126 (E) and 127 (O) remain in flight.
    if (w < 4) {
        ssum += __shfl_xor(ssum, 16);
        ssum += __shfl_xor(ssum, 32);
        if (lg == 0) invl[w * 16 + lr] = 1.0f / ssum;
        asm volatile("s_waitcnt lgkmcnt(0)" ::: "memory");
    }
    asm volatile("" ::: "memory");
    __builtin_amdgcn_s_barrier();
    asm volatile("" ::: "memory");

    // tail B: PV consumes tiles 126 (E), 127 (O); P bank 1.
    if (w >= 4) {
        asm volatile("s_waitcnt vmcnt(4)" ::: "memory");
        __builtin_amdgcn_sched_barrier(0);
        PVSTEP_R(1, 0, E0, E1, E2, E3)
        asm volatile("s_waitcnt vmcnt(0)" ::: "memory");
        __builtin_amdgcn_sched_barrier(0);
        PVSTEP_R(1, 1, O0, O1, O2, O3)

        // epilogue: coalesced out = gamma*acc/l + feat (D[d][q])
        float g = gamma[0];
        float iq0 = invl[lr], iq1 = invl[16 + lr], iq2 = invl[32 + lr], iq3 = invl[48 + lr];
        #pragma unroll
        for (int dt = 0; dt < 4; ++dt) {
            #pragma unroll
            for (int r = 0; r < 4; ++r) {
                size_t row = ((size_t)b * C_ + ds * 64 + dt * 16 + lg * 4 + r) * N_;
                size_t i0r = row + i0;
                { size_t idx = i0r + lr;      out[idx] = g * acc[dt][0][r] * iq0 + feat[idx]; }
                { size_t idx = i0r + 16 + lr; out[idx] = g * acc[dt][1][r] * iq1 + feat[idx]; }
                { size_t idx = i0r + 32 + lr; out[idx] = g * acc[dt][2][r] * iq2 + feat[idx]; }
                { size_t idx = i0r + 48 + lr; out[idx] = g * acc[dt][3][r] * iq3 + feat[idx]; }
            }
        }
    }
#undef PVSTEP_R
#undef SOFTMAX_WRITE
#undef VFETCH4
#undef VLOAD
}

// ---------------------------------------------------------------- launch
extern "C" void kernel_launch(void* const* d_in, const int* in_sizes, int n_in,
                              void* d_out, int out_size, void* d_ws, size_t ws_size,
                              hipStream_t stream) {
    const float* feat  = (const float*)d_in[0];
    const float* w1    = (const float*)d_in[1];
    const float* b1    = (const float*)d_in[2];
    const float* w2    = (const float*)d_in[3];
    const float* b2    = (const float*)d_in[4];
    const float* w3    = (const float*)d_in[5];
    const float* b3    = (const float*)d_in[6];
    const float* gamma = (const float*)d_in[7];
    float* out = (float*)d_out;

    char* ws = (char*)d_ws;
    ushort_t* Xt      = (ushort_t*)(ws);
    ushort_t* Wb      = (ushort_t*)(ws + 16777216);
    float*    biasAll = (float*)   (ws + 17432576);
    ushort_t* QKp     = (ushort_t*)(ws + 17435136);
    ushort_t* Vp      = (ushort_t*)(ws + 21629440);
    if (ws_size < 38406656) return;

    hipLaunchKernelGGL(transpose_cast_x, dim3(64, 8, 5), dim3(256), 0, stream,
                       feat, Xt, w1, b1, w2, b2, w3, b3, Wb, biasAll);
    hipLaunchKernelGGL(gemm_qkv_kernel, dim3(32, 20), dim3(256), 0, stream,
                       Xt, Wb, biasAll, QKp, Vp);
    hipLaunchKernelGGL(attn_kernel, dim3(256), dim3(768), 0, stream,
                       QKp, Vp, feat, gamma, out);
}

// Round 5
// 173.773 us; speedup vs baseline: 1.0909x; 1.0909x over previous
//
#include <hip/hip_runtime.h>
#include <hip/hip_bf16.h>

typedef __attribute__((ext_vector_type(8))) short bf16x8_t;
typedef __attribute__((ext_vector_type(4))) float f32x4_t;

#define B_   4
#define C_   512
#define N_   4096
#define NQK_ 128   // Q(64) | K(64) channel-concat width
#define NT_  128   // N_/32 j-tiles
#define NP_  64    // 2-tile barrier periods

typedef unsigned short ushort_t;

__device__ __forceinline__ ushort_t f2bf(float f) {
    union { float f; unsigned int u; } un; un.f = f;
    unsigned int r = un.u + 0x7FFF + ((un.u >> 16) & 1); // RNE
    return (ushort_t)(r >> 16);
}

__device__ __forceinline__ bf16x8_t load8(const ushort_t* p) {
    return *reinterpret_cast<const bf16x8_t*>(p);
}

__device__ __forceinline__ unsigned pk2(float lo, float hi) {
    return (unsigned)f2bf(lo) | ((unsigned)f2bf(hi) << 16);
}

// async global->LDS, 16B per lane; dest is wave-uniform base (+ lane*16 in HW)
#define GLL16(g, l) __builtin_amdgcn_global_load_lds( \
    (const __attribute__((address_space(1))) unsigned int*)(g), \
    (__attribute__((address_space(3))) unsigned int*)(l), 16, 0, 0)

// ------------------------------------------- transpose+cast x -> Xt[b][n][c]
// z==4: weight/bias cast (folded-in former cast_w kernel)
__global__ __launch_bounds__(256) void transpose_cast_x(
        const float* __restrict__ x, ushort_t* __restrict__ Xt,
        const float* __restrict__ w1, const float* __restrict__ b1,
        const float* __restrict__ w2, const float* __restrict__ b2,
        const float* __restrict__ w3, const float* __restrict__ b3,
        ushort_t* __restrict__ Wb, float* __restrict__ bias_all) {
    if (blockIdx.z == 4) {
        int bid = blockIdx.y * 64 + blockIdx.x;          // 0..511
        int t0 = bid * 256 + threadIdx.x;                // 0..131071
        for (int idx = t0; idx < 640 * 512 + 640; idx += 131072) {
            if (idx < 64 * 512) {
                Wb[idx] = f2bf(w1[idx]);
            } else if (idx < 128 * 512) {
                Wb[idx] = f2bf(w2[idx - 64 * 512]);
            } else if (idx < 640 * 512) {
                Wb[idx] = f2bf(w3[idx - 128 * 512]);
            } else {
                int i = idx - 640 * 512;
                bias_all[i] = (i < 64) ? b1[i] : (i < 128 ? b2[i - 64] : b3[i - 128]);
            }
        }
        return;
    }
    int b = blockIdx.z, c0 = blockIdx.y * 64, n0 = blockIdx.x * 64;
    int tid = threadIdx.x;
    __shared__ float t[64][65];
    const float* xb = x + ((size_t)b * C_ + c0) * N_ + n0;
    // load phase: lane covers c-row (tid>>4), 4 consecutive n (tid&15)*4
    #pragma unroll
    for (int it = 0; it < 4; ++it) {
        int cl = it * 16 + (tid >> 4), nq = (tid & 15) * 4;
        const float4 v = *reinterpret_cast<const float4*>(xb + (size_t)cl * N_ + nq);
        t[cl][nq + 0] = v.x; t[cl][nq + 1] = v.y;
        t[cl][nq + 2] = v.z; t[cl][nq + 3] = v.w;
    }
    __syncthreads();
    // store phase: lane covers n-row (tid>>4), 4 consecutive c (tid&15)*4
    #pragma unroll
    for (int it = 0; it < 4; ++it) {
        int nl = it * 16 + (tid >> 4), cq = (tid & 15) * 4;
        ushort4 o;
        o.x = f2bf(t[cq + 0][nl]); o.y = f2bf(t[cq + 1][nl]);
        o.z = f2bf(t[cq + 2][nl]); o.w = f2bf(t[cq + 3][nl]);
        *reinterpret_cast<ushort4*>(&Xt[((size_t)b * N_ + n0 + nl) * C_ + c0 + cq]) = o;
    }
}

// ---------------------------------------------------- fused QK + V GEMMs
// grid (32, 20). Register double-buffered K-loop (round 14, kept).
__global__ __launch_bounds__(256) void gemm_qkv_kernel(
        const ushort_t* __restrict__ Xt, const ushort_t* __restrict__ Wb,
        const float* __restrict__ bias, ushort_t* __restrict__ QK,
        ushort_t* __restrict__ V) {
    int sel = blockIdx.y;
    int n0 = blockIdx.x * 128;
    int tid = threadIdx.x;
    int l = tid & 63, w = tid >> 6;
    int wr = w >> 1, wc = w & 1;
    int lr = l & 15, lg = l >> 4;
    if (sel < 4) {
        int b = sel;
        const ushort_t* Xb = Xt + (size_t)b * N_ * C_;
        const ushort_t* ap = Xb + (size_t)(n0 + wr * 64 + lr) * 512 + lg * 8;
        const ushort_t* bp = Wb + (size_t)(wc * 64 + lr) * 512 + lg * 8;
        f32x4_t acc[4][4] = {};
        bf16x8_t a[4], bb[4];
        #pragma unroll
        for (int f = 0; f < 4; ++f) {
            a[f]  = load8(ap + (size_t)f * 16 * 512);
            bb[f] = load8(bp + (size_t)f * 16 * 512);
        }
        for (int kk = 0; kk < 512; kk += 32) {
            bf16x8_t na[4], nbb[4];
            if (kk + 32 < 512) {
                #pragma unroll
                for (int f = 0; f < 4; ++f) {
                    na[f]  = load8(ap + (size_t)f * 16 * 512 + kk + 32);
                    nbb[f] = load8(bp + (size_t)f * 16 * 512 + kk + 32);
                }
            }
            #pragma unroll
            for (int fi = 0; fi < 4; ++fi)
                #pragma unroll
                for (int fj = 0; fj < 4; ++fj)
                    acc[fi][fj] = __builtin_amdgcn_mfma_f32_16x16x32_bf16(
                        a[fi], bb[fj], acc[fi][fj], 0, 0, 0);
            if (kk + 32 < 512) {
                #pragma unroll
                for (int f = 0; f < 4; ++f) { a[f] = na[f]; bb[f] = nbb[f]; }
            }
        }
        #pragma unroll
        for (int fi = 0; fi < 4; ++fi)
            #pragma unroll
            for (int fj = 0; fj < 4; ++fj)
                #pragma unroll
                for (int r = 0; r < 4; ++r) {
                    int n = n0 + wr * 64 + fi * 16 + lg * 4 + r;
                    int col = wc * 64 + fj * 16 + lr;
                    QK[((size_t)b * N_ + n) * NQK_ + col] = f2bf(acc[fi][fj][r] + bias[col]);
                }
    } else {
        int m0 = ((sel - 4) & 3) * 128;
        int b  = (sel - 4) >> 2;
        const ushort_t* Xb = Xt + (size_t)b * N_ * C_;
        const ushort_t* Wv = Wb + 128 * 512;
        const ushort_t* ap = Wv + (size_t)(m0 + wr * 64 + lr) * 512 + lg * 8;
        const ushort_t* bp = Xb + (size_t)(n0 + wc * 64 + lr) * 512 + lg * 8;
        f32x4_t acc[4][4] = {};
        bf16x8_t a[4], bb[4];
        #pragma unroll
        for (int f = 0; f < 4; ++f) {
            a[f]  = load8(ap + (size_t)f * 16 * 512);
            bb[f] = load8(bp + (size_t)f * 16 * 512);
        }
        for (int kk = 0; kk < 512; kk += 32) {
            bf16x8_t na[4], nbb[4];
            if (kk + 32 < 512) {
                #pragma unroll
                for (int f = 0; f < 4; ++f) {
                    na[f]  = load8(ap + (size_t)f * 16 * 512 + kk + 32);
                    nbb[f] = load8(bp + (size_t)f * 16 * 512 + kk + 32);
                }
            }
            #pragma unroll
            for (int fi = 0; fi < 4; ++fi)
                #pragma unroll
                for (int fj = 0; fj < 4; ++fj)
                    acc[fi][fj] = __builtin_amdgcn_mfma_f32_16x16x32_bf16(
                        a[fi], bb[fj], acc[fi][fj], 0, 0, 0);
            if (kk + 32 < 512) {
                #pragma unroll
                for (int f = 0; f < 4; ++f) { a[f] = na[f]; bb[f] = nbb[f]; }
            }
        }
        #pragma unroll
        for (int fi = 0; fi < 4; ++fi)
            #pragma unroll
            for (int fj = 0; fj < 4; ++fj)
                #pragma unroll
                for (int r = 0; r < 4; ++r) {
                    int d = m0 + wr * 64 + fi * 16 + lg * 4 + r;
                    int n = n0 + wc * 64 + fj * 16 + lr;
                    V[((size_t)b * C_ + d) * N_ + n] = f2bf(acc[fi][fj][r] + bias[128 + d]);
                }
    }
}

// ---------------------------------------------------- fused flash attention
// grid 256 x 768thr (12 waves). Round 23: V stays on GLL16 DMA (rounds
// 19/20/22 proved global->VGPR V costs +21% regardless of waitcnt discipline
// — return-path stall, not scheduling). Change vs round-0 structure: V stage
// distance 3 -> 2. With distance 3, the stage target buffer equals the buffer
// being read (j%3 == (j+3)%3), forcing a hard lgkmcnt(0) drain before each
// stage (2x/period, ~250cyc exposed each). With distance 2 the stage targets
// the buffer freed by the PREVIOUS PVSTEP's reads, whose completion is
// already implied by its MFMAs' data dependence (in-order DS queue) — so:
// no lgkmcnt(0); stage moved to PVSTEP end; rescale overlaps vf latency;
// the end-of-period vmcnt(4) is replaced by a vmcnt(4) before each vf read
// block, protecting exactly the tile being read (staged a full period ago).
// All V hazards are within-wave (each PV wave stages/reads only its own
// 64-channel LDS slice).
__global__ __launch_bounds__(768, 3) void attn_kernel(
        const ushort_t* __restrict__ QK, const ushort_t* __restrict__ V,
        const float* __restrict__ feat, const float* __restrict__ gamma,
        float* __restrict__ out) {
    __shared__ ushort_t Vl[3][16384];                // V tile [512d][32j] x3, swizzled
    __shared__ ushort_t Kl3[3][4096];                // K 2-tile bufs x3, XOR-swizzled
    __shared__ ushort_t Pl[2][4096];                 // P banks (2 tiles each)
    __shared__ float    fl[2][128];                  // per-q rescale, [bank][tt*64+q]
    __shared__ __align__(16) unsigned flagl[2][8];   // [bank][tt*4+qt]
    __shared__ float    invl[64];                    // final 1/ssum per q

    int bid = blockIdx.x;
    int lid = (bid & 7) * 32 + (bid >> 3);  // XCD-contiguous: one batch per 2 XCDs
    int b  = lid >> 6;
    int i0 = (lid & 63) * 64;

    int tid = threadIdx.x;
    int l = tid & 63, w = tid >> 6;
    int lr = l & 15, lg = l >> 4;
    int ds = (w >= 4) ? (w - 4) : 0;        // 0..7, 64-channel slice

    const ushort_t* QKb = QK + (size_t)b * N_ * NQK_;
    const ushort_t* Vb  = V  + (size_t)b * C_ * N_;

    // ---- S-wave persistent state
    bf16x8_t qf0 = {}, qf1 = {};
    const ushort_t* ksrc = nullptr;
    float mreg = -1e30f, ssum = 0.0f;       // ssum group-partial (reduced at end)
    const int maskk = (lr & 7) << 4;  // K read swizzle
    if (w < 4) {
        qf0 = load8(QKb + (size_t)(i0 + w * 16 + lr) * NQK_ + lg * 8);
        qf1 = load8(QKb + (size_t)(i0 + w * 16 + lr) * NQK_ + 32 + lg * 8);
        int p = w * 1024 + l * 16;
        int o = p ^ (((p >> 7) & 7) << 4);
        ksrc = QKb + (size_t)(o >> 7) * NQK_ + 64 + ((o & 127) >> 1);
    }

    // ---- PV-wave persistent state (round-8 V layout, verbatim)
    int cst = (l & 7) ^ (l >> 3);
    const ushort_t* vsrc = Vb + (size_t)(ds * 64 + 2 * (l >> 3) + (cst >> 2)) * N_
                              + (cst & 3) * 8;
    int c2 = ((lr & 1) * 4 + lg) ^ (lr >> 1);
    const int vread = ds * 2048 + (lr >> 1) * 64 + c2 * 8;   // ushorts; + dt*512
    f32x4_t acc[4][4] = {};

    // prologue: S stages K periods 0,1 (buf0,buf1), waits buf0 (buf1 in flight).
    // PV stages V tiles 0,1 into bufs 0,1 (distance-2 pipeline: period p
    // stages tiles 2p,2p+1 for consumption at p+1).
    if (w < 4) {
        GLL16(ksrc,                         &Kl3[0][w * 512]);
        GLL16(ksrc + (size_t)1 * 32 * NQK_, &Kl3[0][2048 + w * 512]);
        GLL16(ksrc + (size_t)2 * 32 * NQK_, &Kl3[1][w * 512]);
        GLL16(ksrc + (size_t)3 * 32 * NQK_, &Kl3[1][2048 + w * 512]);
        asm volatile("s_waitcnt vmcnt(2)" ::: "memory");
    } else {
        #pragma unroll
        for (int h = 0; h < 4; ++h)
            GLL16(vsrc + (size_t)h * 16 * N_,      &Vl[0][ds * 2048 + h * 512]);
        #pragma unroll
        for (int h = 0; h < 4; ++h)
            GLL16(vsrc + (size_t)h * 16 * N_ + 32, &Vl[1][ds * 2048 + h * 512]);
    }
    asm volatile("" ::: "memory");
    __builtin_amdgcn_s_barrier();
    asm volatile("" ::: "memory");

#define SOFTMAX_WRITE(SO0, SO1, PM, TT)                                        \
    {                                                                          \
        float pmax = fmaxf(fmaxf(fmaxf(SO0[0],SO0[1]), fmaxf(SO0[2],SO0[3])),  \
                           fmaxf(fmaxf(SO1[0],SO1[1]), fmaxf(SO1[2],SO1[3]))); \
        pmax = fmaxf(pmax, __shfl_xor(pmax, 16));                              \
        pmax = fmaxf(pmax, __shfl_xor(pmax, 32));                              \
        bool anyneed = __any(pmax > mreg + 8.0f);                              \
        if (anyneed) {                                                         \
            float mn = fmaxf(mreg, pmax);                                      \
            float f_ = __expf(mreg - mn);                                      \
            mreg = mn; ssum *= f_;                                             \
            if (lg == 0) fl[PM][(TT) * 64 + w * 16 + lr] = f_;                 \
        }                                                                      \
        if (l == 0) flagl[PM][(TT) * 4 + w] = anyneed ? 1u : 0u;               \
        float e00 = __expf(SO0[0]-mreg), e01 = __expf(SO0[1]-mreg);            \
        float e02 = __expf(SO0[2]-mreg), e03 = __expf(SO0[3]-mreg);            \
        float e10 = __expf(SO1[0]-mreg), e11 = __expf(SO1[1]-mreg);            \
        float e12 = __expf(SO1[2]-mreg), e13 = __expf(SO1[3]-mreg);            \
        ssum += (e00+e01)+(e02+e03)+(e10+e11)+(e12+e13);  /* group-partial */  \
        int lt = lr + (lg >> 1) * 16;                                          \
        uint2 w0v; w0v.x = pk2(e00, e01); w0v.y = pk2(e02, e03);               \
        uint2 w1v; w1v.x = pk2(e10, e11); w1v.y = pk2(e12, e13);               \
        *reinterpret_cast<uint2*>(&Pl[PM][(TT)*2048 + w*512 + lt*8 + (lg&1)*4]) = w0v; \
        *reinterpret_cast<uint2*>(&Pl[PM][(TT)*2048 + w*512 + (lt+32)*8 + (lg&1)*4]) = w1v; \
    }

// PV: consume tile (P bank PB, slot TT, V buf VB), then stage tile STJ into
// buf SB (!= VB; freed by the previous PVSTEP/period — its reads' completion
// is implied by the MFMA data dependence on vf, in-order DS queue, so no
// lgkmcnt(0) is needed). Caller places the vmcnt wait protecting VB's data.
#define PVSTEP(PB, TT, VB, SB, STJ, DOSTAGE)                                   \
    {                                                                          \
        bf16x8_t vf[4];                                                        \
        _Pragma("unroll") for (int dt = 0; dt < 4; ++dt)                       \
            vf[dt] = load8(&Vl[VB][vread + dt * 512]);                         \
        uint4 fv = *reinterpret_cast<const uint4*>(&flagl[PB][(TT) * 4]);      \
        if ((int)__builtin_amdgcn_readfirstlane(fv.x)) {                       \
            float fq = fl[PB][(TT) * 64 + lr];                                 \
            _Pragma("unroll") for (int dt = 0; dt < 4; ++dt) acc[dt][0] *= fq; \
        }                                                                      \
        if ((int)__builtin_amdgcn_readfirstlane(fv.y)) {                       \
            float fq = fl[PB][(TT) * 64 + 16 + lr];                            \
            _Pragma("unroll") for (int dt = 0; dt < 4; ++dt) acc[dt][1] *= fq; \
        }                                                                      \
        if ((int)__builtin_amdgcn_readfirstlane(fv.z)) {                       \
            float fq = fl[PB][(TT) * 64 + 32 + lr];                            \
            _Pragma("unroll") for (int dt = 0; dt < 4; ++dt) acc[dt][2] *= fq; \
        }                                                                      \
        if ((int)__builtin_amdgcn_readfirstlane(fv.w)) {                       \
            float fq = fl[PB][(TT) * 64 + 48 + lr];                            \
            _Pragma("unroll") for (int dt = 0; dt < 4; ++dt) acc[dt][3] *= fq; \
        }                                                                      \
        __builtin_amdgcn_s_setprio(1);                                         \
        _Pragma("unroll") for (int qt = 0; qt < 4; ++qt) {                     \
            bf16x8_t pa = load8(&Pl[PB][(TT) * 2048 + qt * 512 + l * 8]);      \
            _Pragma("unroll") for (int dt = 0; dt < 4; ++dt)                   \
                acc[dt][qt] = __builtin_amdgcn_mfma_f32_16x16x32_bf16(         \
                    vf[dt], pa, acc[dt][qt], 0, 0, 0);                         \
        }                                                                      \
        __builtin_amdgcn_s_setprio(0);                                         \
        if (DOSTAGE) {                                                         \
            const ushort_t* vsT = vsrc + (STJ) * 32;                           \
            _Pragma("unroll") for (int h = 0; h < 4; ++h)                      \
                GLL16(vsT + (size_t)h * 16 * N_, &Vl[SB][ds * 2048 + h * 512]); \
        }                                                                      \
    }

    for (int p = 0; p < NP_; ++p) {
        int pb = p % 3;
        if (w < 4) {
            // stage K for period p+2
            if (p + 2 < NP_) {
                int pn = pb + 2; if (pn >= 3) pn -= 3;
                GLL16(ksrc + (size_t)(2 * p + 4) * 32 * NQK_, &Kl3[pn][w * 512]);
                GLL16(ksrc + (size_t)(2 * p + 5) * 32 * NQK_, &Kl3[pn][2048 + w * 512]);
            }
            const ushort_t* kbp = &Kl3[pb][0];
            // tile 2p
            bf16x8_t kf00, kf01, kf10, kf11;
            { int o = (lr << 7) + (lg << 4);              kf00 = load8(kbp + ((o ^ maskk) >> 1)); }
            { int o = (lr << 7) + 64 + (lg << 4);         kf01 = load8(kbp + ((o ^ maskk) >> 1)); }
            { int o = ((16 + lr) << 7) + (lg << 4);       kf10 = load8(kbp + ((o ^ maskk) >> 1)); }
            { int o = ((16 + lr) << 7) + 64 + (lg << 4);  kf11 = load8(kbp + ((o ^ maskk) >> 1)); }
            f32x4_t s00 = {0.f,0.f,0.f,0.f}, s01 = {0.f,0.f,0.f,0.f};
            s00 = __builtin_amdgcn_mfma_f32_16x16x32_bf16(kf00, qf0, s00, 0,0,0);
            s00 = __builtin_amdgcn_mfma_f32_16x16x32_bf16(kf01, qf1, s00, 0,0,0);
            s01 = __builtin_amdgcn_mfma_f32_16x16x32_bf16(kf10, qf0, s01, 0,0,0);
            s01 = __builtin_amdgcn_mfma_f32_16x16x32_bf16(kf11, qf1, s01, 0,0,0);
            // tile 2p+1
            const ushort_t* kbq = kbp + 2048;
            bf16x8_t kg00, kg01, kg10, kg11;
            { int o = (lr << 7) + (lg << 4);              kg00 = load8(kbq + ((o ^ maskk) >> 1)); }
            { int o = (lr << 7) + 64 + (lg << 4);         kg01 = load8(kbq + ((o ^ maskk) >> 1)); }
            { int o = ((16 + lr) << 7) + (lg << 4);       kg10 = load8(kbq + ((o ^ maskk) >> 1)); }
            { int o = ((16 + lr) << 7) + 64 + (lg << 4);  kg11 = load8(kbq + ((o ^ maskk) >> 1)); }
            f32x4_t s10 = {0.f,0.f,0.f,0.f}, s11 = {0.f,0.f,0.f,0.f};
            s10 = __builtin_amdgcn_mfma_f32_16x16x32_bf16(kg00, qf0, s10, 0,0,0);
            s10 = __builtin_amdgcn_mfma_f32_16x16x32_bf16(kg01, qf1, s10, 0,0,0);
            s11 = __builtin_amdgcn_mfma_f32_16x16x32_bf16(kg10, qf0, s11, 0,0,0);
            s11 = __builtin_amdgcn_mfma_f32_16x16x32_bf16(kg11, qf1, s11, 0,0,0);
            // softmax 2p (while 2p+1's MFMAs retire), then 2p+1
            int bank = p & 1;
            SOFTMAX_WRITE(s00, s01, bank, 0)
            SOFTMAX_WRITE(s10, s11, bank, 1)
            asm volatile("s_waitcnt vmcnt(2) lgkmcnt(0)" ::: "memory");
        } else {
            if (p >= 1) {
                int pbk = (p - 1) & 1;
                int j0 = 2 * p - 2, j1 = 2 * p - 1;
                // consume j0 (staged one period ago; since then only j1's 4
                // loads were issued) -> vmcnt(4); stage j0+2 into (j0+2)%3.
                asm volatile("s_waitcnt vmcnt(4)" ::: "memory");
                PVSTEP(pbk, 0, j0 % 3, (j0 + 2) % 3, j0 + 2, true)
                // consume j1 (since its stage, only (j0+2)'s 4 loads issued)
                asm volatile("s_waitcnt vmcnt(4)" ::: "memory");
                PVSTEP(pbk, 1, j1 % 3, (j1 + 2) % 3, j1 + 2, true)
            }
            // period 0: prologue staged tiles 0,1; nothing to consume.
        }
        asm volatile("" ::: "memory");
        __builtin_amdgcn_s_barrier();
        asm volatile("" ::: "memory");
    }

    // tail A: S reduces group-partial ssum, publishes invl.
    // PV's stages for tiles 126,127 (issued at p=63) remain in flight.
    if (w < 4) {
        ssum += __shfl_xor(ssum, 16);
        ssum += __shfl_xor(ssum, 32);
        if (lg == 0) invl[w * 16 + lr] = 1.0f / ssum;
        asm volatile("s_waitcnt lgkmcnt(0)" ::: "memory");
    }
    asm volatile("" ::: "memory");
    __builtin_amdgcn_s_barrier();
    asm volatile("" ::: "memory");

    // tail B: PV consumes tiles 126 (buf 0), 127 (buf 1); P bank 1.
    if (w >= 4) {
        asm volatile("s_waitcnt vmcnt(4)" ::: "memory");   // tile 126 landed
        PVSTEP(1, 0, 0, 0, 0, false)
        asm volatile("s_waitcnt vmcnt(0)" ::: "memory");   // tile 127 landed
        PVSTEP(1, 1, 1, 1, 0, false)
        asm volatile("s_waitcnt lgkmcnt(0)" ::: "memory");

        // epilogue: coalesced out = gamma*acc/l + feat (D[d][q])
        float g = gamma[0];
        float iq0 = invl[lr], iq1 = invl[16 + lr], iq2 = invl[32 + lr], iq3 = invl[48 + lr];
        #pragma unroll
        for (int dt = 0; dt < 4; ++dt) {
            #pragma unroll
            for (int r = 0; r < 4; ++r) {
                size_t row = ((size_t)b * C_ + ds * 64 + dt * 16 + lg * 4 + r) * N_;
                size_t i0r = row + i0;
                { size_t idx = i0r + lr;      out[idx] = g * acc[dt][0][r] * iq0 + feat[idx]; }
                { size_t idx = i0r + 16 + lr; out[idx] = g * acc[dt][1][r] * iq1 + feat[idx]; }
                { size_t idx = i0r + 32 + lr; out[idx] = g * acc[dt][2][r] * iq2 + feat[idx]; }
                { size_t idx = i0r + 48 + lr; out[idx] = g * acc[dt][3][r] * iq3 + feat[idx]; }
            }
        }
    }
#undef PVSTEP
#undef SOFTMAX_WRITE
}

// ---------------------------------------------------------------- launch
extern "C" void kernel_launch(void* const* d_in, const int* in_sizes, int n_in,
                              void* d_out, int out_size, void* d_ws, size_t ws_size,
                              hipStream_t stream) {
    const float* feat  = (const float*)d_in[0];
    const float* w1    = (const float*)d_in[1];
    const float* b1    = (const float*)d_in[2];
    const float* w2    = (const float*)d_in[3];
    const float* b2    = (const float*)d_in[4];
    const float* w3    = (const float*)d_in[5];
    const float* b3    = (const float*)d_in[6];
    const float* gamma = (const float*)d_in[7];
    float* out = (float*)d_out;

    char* ws = (char*)d_ws;
    ushort_t* Xt      = (ushort_t*)(ws);
    ushort_t* Wb      = (ushort_t*)(ws + 16777216);
    float*    biasAll = (float*)   (ws + 17432576);
    ushort_t* QKp     = (ushort_t*)(ws + 17435136);
    ushort_t* Vp      = (ushort_t*)(ws + 21629440);
    if (ws_size < 38406656) return;

    hipLaunchKernelGGL(transpose_cast_x, dim3(64, 8, 5), dim3(256), 0, stream,
                       feat, Xt, w1, b1, w2, b2, w3, b3, Wb, biasAll);
    hipLaunchKernelGGL(gemm_qkv_kernel, dim3(32, 20), dim3(256), 0, stream,
                       Xt, Wb, biasAll, QKp, Vp);
    hipLaunchKernelGGL(attn_kernel, dim3(256), dim3(768), 0, stream,
                       QKp, Vp, feat, gamma, out);
}

// Round 6
// 139.697 us; speedup vs baseline: 1.3570x; 1.2439x over previous
//
#include <hip/hip_runtime.h>
#include <hip/hip_bf16.h>

typedef __attribute__((ext_vector_type(8))) short bf16x8_t;
typedef __attribute__((ext_vector_type(4))) float f32x4_t;

#define B_   4
#define C_   512
#define N_   4096
#define NQK_ 128   // Q(64) | K(64) channel-concat width
#define NT_  128   // N_/32 j-tiles
#define NP_  64    // 2-tile barrier periods

typedef unsigned short ushort_t;

__device__ __forceinline__ ushort_t f2bf(float f) {
    union { float f; unsigned int u; } un; un.f = f;
    unsigned int r = un.u + 0x7FFF + ((un.u >> 16) & 1); // RNE
    return (ushort_t)(r >> 16);
}

__device__ __forceinline__ bf16x8_t load8(const ushort_t* p) {
    return *reinterpret_cast<const bf16x8_t*>(p);
}

__device__ __forceinline__ unsigned pk2(float lo, float hi) {
    return (unsigned)f2bf(lo) | ((unsigned)f2bf(hi) << 16);
}

// async global->LDS, 16B per lane; dest is wave-uniform base (+ lane*16 in HW)
#define GLL16(g, l) __builtin_amdgcn_global_load_lds( \
    (const __attribute__((address_space(1))) unsigned int*)(g), \
    (__attribute__((address_space(3))) unsigned int*)(l), 16, 0, 0)

// ------------------------------------------- transpose+cast x -> Xt[b][n][c]
// z==4: weight/bias cast (folded-in former cast_w kernel)
__global__ __launch_bounds__(256) void transpose_cast_x(
        const float* __restrict__ x, ushort_t* __restrict__ Xt,
        const float* __restrict__ w1, const float* __restrict__ b1,
        const float* __restrict__ w2, const float* __restrict__ b2,
        const float* __restrict__ w3, const float* __restrict__ b3,
        ushort_t* __restrict__ Wb, float* __restrict__ bias_all) {
    if (blockIdx.z == 4) {
        int bid = blockIdx.y * 64 + blockIdx.x;          // 0..511
        int t0 = bid * 256 + threadIdx.x;                // 0..131071
        for (int idx = t0; idx < 640 * 512 + 640; idx += 131072) {
            if (idx < 64 * 512) {
                Wb[idx] = f2bf(w1[idx]);
            } else if (idx < 128 * 512) {
                Wb[idx] = f2bf(w2[idx - 64 * 512]);
            } else if (idx < 640 * 512) {
                Wb[idx] = f2bf(w3[idx - 128 * 512]);
            } else {
                int i = idx - 640 * 512;
                bias_all[i] = (i < 64) ? b1[i] : (i < 128 ? b2[i - 64] : b3[i - 128]);
            }
        }
        return;
    }
    int b = blockIdx.z, c0 = blockIdx.y * 64, n0 = blockIdx.x * 64;
    int tid = threadIdx.x;
    __shared__ float t[64][65];
    const float* xb = x + ((size_t)b * C_ + c0) * N_ + n0;
    // load phase: lane covers c-row (tid>>4), 4 consecutive n (tid&15)*4
    #pragma unroll
    for (int it = 0; it < 4; ++it) {
        int cl = it * 16 + (tid >> 4), nq = (tid & 15) * 4;
        const float4 v = *reinterpret_cast<const float4*>(xb + (size_t)cl * N_ + nq);
        t[cl][nq + 0] = v.x; t[cl][nq + 1] = v.y;
        t[cl][nq + 2] = v.z; t[cl][nq + 3] = v.w;
    }
    __syncthreads();
    // store phase: lane covers n-row (tid>>4), 4 consecutive c (tid&15)*4
    #pragma unroll
    for (int it = 0; it < 4; ++it) {
        int nl = it * 16 + (tid >> 4), cq = (tid & 15) * 4;
        ushort4 o;
        o.x = f2bf(t[cq + 0][nl]); o.y = f2bf(t[cq + 1][nl]);
        o.z = f2bf(t[cq + 2][nl]); o.w = f2bf(t[cq + 3][nl]);
        *reinterpret_cast<ushort4*>(&Xt[((size_t)b * N_ + n0 + nl) * C_ + c0 + cq]) = o;
    }
}

// ---------------------------------------------------- fused QK + V GEMMs
// grid (32, 20). Round 24: m97-style GLL16-staged LDS double buffer replaces
// the no-LDS direct-global-load K-loop. Previous version: 8 per-lane global
// loads per K-step per wave with 1-step register lookahead (~80 MFMA cyc of
// cover vs ~300cyc L2 latency) — the classic ~350-450 TF plateau. m97 recipe
// (874 TF, harness-verified on this shape class): Al/Bl[2][128x32] (32KB),
// 4 GLL16/wave/K-step (width 16), vmcnt(4) cadence, 2 barriers/iter.
// Fragment row/k mapping, MFMA sequence and epilogue are byte-identical to
// the previous (passing) version — only operand routing changed.
__global__ __launch_bounds__(256) void gemm_qkv_kernel(
        const ushort_t* __restrict__ Xt, const ushort_t* __restrict__ Wb,
        const float* __restrict__ bias, ushort_t* __restrict__ QK,
        ushort_t* __restrict__ V) {
    __shared__ ushort_t Al[2][4096];   // 128 rows x 32 k, linear
    __shared__ ushort_t Bl[2][4096];
    int sel = blockIdx.y;
    int n0 = blockIdx.x * 128;
    int tid = threadIdx.x;
    int l = tid & 63, w = tid >> 6;
    int wr = w >> 1, wc = w & 1;
    int lr = l & 15, lg = l >> 4;

    int m0 = 0, bV = 0;
    const ushort_t* asrc;
    const ushort_t* bsrc;
    if (sel < 4) {
        asrc = Xt + ((size_t)sel * N_ + n0) * 512;     // A rows = n-rows
        bsrc = Wb;                                     // B rows = 128 qk cols
    } else {
        m0 = ((sel - 4) & 3) * 128;
        bV = (sel - 4) >> 2;
        asrc = Wb + (size_t)(128 + m0) * 512;          // A rows = d-rows of Wv
        bsrc = Xt + ((size_t)bV * N_ + n0) * 512;      // B rows = n-rows
    }
    // per-lane stage source: call covers 16 rows; lane l -> row l>>2,
    // k-offset (l&3)*8 (matches GLL16's dest = base + lane*16B).
    const ushort_t* ast = asrc + (size_t)(l >> 2) * 512 + (l & 3) * 8;
    const ushort_t* bst = bsrc + (size_t)(l >> 2) * 512 + (l & 3) * 8;

#define STAGEK(BUF, K0)                                                        \
    {                                                                          \
        GLL16(ast + (size_t)(w * 32) * 512 + (K0),      &Al[BUF][w * 1024]);       \
        GLL16(ast + (size_t)(w * 32 + 16) * 512 + (K0), &Al[BUF][w * 1024 + 512]); \
        GLL16(bst + (size_t)(w * 32) * 512 + (K0),      &Bl[BUF][w * 1024]);       \
        GLL16(bst + (size_t)(w * 32 + 16) * 512 + (K0), &Bl[BUF][w * 1024 + 512]); \
    }

    f32x4_t acc[4][4] = {};
    STAGEK(0, 0)
    for (int i = 0; i < 16; ++i) {
        int cur = i & 1;
        if (i < 15) {
            STAGEK(cur ^ 1, (i + 1) * 32)
            asm volatile("s_waitcnt vmcnt(4)" ::: "memory");  // cur's 4 landed
        } else {
            asm volatile("s_waitcnt vmcnt(0)" ::: "memory");
        }
        asm volatile("" ::: "memory");
        __builtin_amdgcn_s_barrier();
        asm volatile("" ::: "memory");
        bf16x8_t a[4], b8[4];
        #pragma unroll
        for (int f = 0; f < 4; ++f) {
            a[f]  = load8(&Al[cur][(wr * 64 + f * 16 + lr) * 32 + lg * 8]);
            b8[f] = load8(&Bl[cur][(wc * 64 + f * 16 + lr) * 32 + lg * 8]);
        }
        #pragma unroll
        for (int fi = 0; fi < 4; ++fi)
            #pragma unroll
            for (int fj = 0; fj < 4; ++fj)
                acc[fi][fj] = __builtin_amdgcn_mfma_f32_16x16x32_bf16(
                    a[fi], b8[fj], acc[fi][fj], 0, 0, 0);
        asm volatile("" ::: "memory");
        __builtin_amdgcn_s_barrier();   // all reads of cur done before it is re-staged
        asm volatile("" ::: "memory");
    }
#undef STAGEK

    if (sel < 4) {
        #pragma unroll
        for (int fi = 0; fi < 4; ++fi)
            #pragma unroll
            for (int fj = 0; fj < 4; ++fj)
                #pragma unroll
                for (int r = 0; r < 4; ++r) {
                    int n = n0 + wr * 64 + fi * 16 + lg * 4 + r;
                    int col = wc * 64 + fj * 16 + lr;
                    QK[((size_t)sel * N_ + n) * NQK_ + col] = f2bf(acc[fi][fj][r] + bias[col]);
                }
    } else {
        #pragma unroll
        for (int fi = 0; fi < 4; ++fi)
            #pragma unroll
            for (int fj = 0; fj < 4; ++fj)
                #pragma unroll
                for (int r = 0; r < 4; ++r) {
                    int d = m0 + wr * 64 + fi * 16 + lg * 4 + r;
                    int n = n0 + wc * 64 + fj * 16 + lr;
                    V[((size_t)bV * C_ + d) * N_ + n] = f2bf(acc[fi][fj][r] + bias[128 + d]);
                }
    }
}

// ---------------------------------------------------- fused flash attention
// grid 256 x 768thr (12 waves). Round-0 structure (119us) restored verbatim:
// V via GLL16 DMA staging, distance-3, lgkm(0)+vmcnt(4) cadence. Five
// restructurings (V-in-reg x3, setprio, distance-2) all regressed or were
// null — this schedule is a measured local optimum. setprio kept (null,
// harmless).
__global__ __launch_bounds__(768, 3) void attn_kernel(
        const ushort_t* __restrict__ QK, const ushort_t* __restrict__ V,
        const float* __restrict__ feat, const float* __restrict__ gamma,
        float* __restrict__ out) {
    __shared__ ushort_t Vl[3][16384];                // V tile [512d][32j] x3, swizzled
    __shared__ ushort_t Kl3[3][4096];                // K 2-tile bufs x3, XOR-swizzled
    __shared__ ushort_t Pl[2][4096];                 // P banks (2 tiles each)
    __shared__ float    fl[2][128];                  // per-q rescale, [bank][tt*64+q]
    __shared__ __align__(16) unsigned flagl[2][8];   // [bank][tt*4+qt]
    __shared__ float    invl[64];                    // final 1/ssum per q

    int bid = blockIdx.x;
    int lid = (bid & 7) * 32 + (bid >> 3);  // XCD-contiguous: one batch per 2 XCDs
    int b  = lid >> 6;
    int i0 = (lid & 63) * 64;

    int tid = threadIdx.x;
    int l = tid & 63, w = tid >> 6;
    int lr = l & 15, lg = l >> 4;
    int ds = (w >= 4) ? (w - 4) : 0;        // 0..7, 64-channel slice

    const ushort_t* QKb = QK + (size_t)b * N_ * NQK_;
    const ushort_t* Vb  = V  + (size_t)b * C_ * N_;

    // ---- S-wave persistent state
    bf16x8_t qf0 = {}, qf1 = {};
    const ushort_t* ksrc = nullptr;
    float mreg = -1e30f, ssum = 0.0f;       // ssum group-partial (reduced at end)
    const int maskk = (lr & 7) << 4;  // K read swizzle
    if (w < 4) {
        qf0 = load8(QKb + (size_t)(i0 + w * 16 + lr) * NQK_ + lg * 8);
        qf1 = load8(QKb + (size_t)(i0 + w * 16 + lr) * NQK_ + 32 + lg * 8);
        int p = w * 1024 + l * 16;
        int o = p ^ (((p >> 7) & 7) << 4);
        ksrc = QKb + (size_t)(o >> 7) * NQK_ + 64 + ((o & 127) >> 1);
    }

    // ---- PV-wave persistent state (round-8 V layout, verbatim)
    int cst = (l & 7) ^ (l >> 3);
    const ushort_t* vsrc = Vb + (size_t)(ds * 64 + 2 * (l >> 3) + (cst >> 2)) * N_
                              + (cst & 3) * 8;
    int c2 = ((lr & 1) * 4 + lg) ^ (lr >> 1);
    const int vread = ds * 2048 + (lr >> 1) * 64 + c2 * 8;   // ushorts; + dt*512
    f32x4_t acc[4][4] = {};

    // prologue: S stages K periods 0,1 (buf0,buf1), waits buf0 (buf1 in flight).
    // PV stages V(0),V(1),V(2) into bufs 0,1,2 (retired under vmcnt(4) cadence).
    if (w < 4) {
        GLL16(ksrc,                         &Kl3[0][w * 512]);
        GLL16(ksrc + (size_t)1 * 32 * NQK_, &Kl3[0][2048 + w * 512]);
        GLL16(ksrc + (size_t)2 * 32 * NQK_, &Kl3[1][w * 512]);
        GLL16(ksrc + (size_t)3 * 32 * NQK_, &Kl3[1][2048 + w * 512]);
        asm volatile("s_waitcnt vmcnt(2)" ::: "memory");
    } else {
        #pragma unroll
        for (int h = 0; h < 4; ++h)
            GLL16(vsrc + (size_t)h * 16 * N_,      &Vl[0][ds * 2048 + h * 512]);
        #pragma unroll
        for (int h = 0; h < 4; ++h)
            GLL16(vsrc + (size_t)h * 16 * N_ + 32, &Vl[1][ds * 2048 + h * 512]);
        #pragma unroll
        for (int h = 0; h < 4; ++h)
            GLL16(vsrc + (size_t)h * 16 * N_ + 64, &Vl[2][ds * 2048 + h * 512]);
    }
    asm volatile("" ::: "memory");
    __builtin_amdgcn_s_barrier();
    asm volatile("" ::: "memory");

#define SOFTMAX_WRITE(SO0, SO1, PM, TT)                                        \
    {                                                                          \
        float pmax = fmaxf(fmaxf(fmaxf(SO0[0],SO0[1]), fmaxf(SO0[2],SO0[3])),  \
                           fmaxf(fmaxf(SO1[0],SO1[1]), fmaxf(SO1[2],SO1[3]))); \
        pmax = fmaxf(pmax, __shfl_xor(pmax, 16));                              \
        pmax = fmaxf(pmax, __shfl_xor(pmax, 32));                              \
        bool anyneed = __any(pmax > mreg + 8.0f);                              \
        if (anyneed) {                                                         \
            float mn = fmaxf(mreg, pmax);                                      \
            float f_ = __expf(mreg - mn);                                      \
            mreg = mn; ssum *= f_;                                             \
            if (lg == 0) fl[PM][(TT) * 64 + w * 16 + lr] = f_;                 \
        }                                                                      \
        if (l == 0) flagl[PM][(TT) * 4 + w] = anyneed ? 1u : 0u;               \
        float e00 = __expf(SO0[0]-mreg), e01 = __expf(SO0[1]-mreg);            \
        float e02 = __expf(SO0[2]-mreg), e03 = __expf(SO0[3]-mreg);            \
        float e10 = __expf(SO1[0]-mreg), e11 = __expf(SO1[1]-mreg);            \
        float e12 = __expf(SO1[2]-mreg), e13 = __expf(SO1[3]-mreg);            \
        ssum += (e00+e01)+(e02+e03)+(e10+e11)+(e12+e13);  /* group-partial */  \
        int lt = lr + (lg >> 1) * 16;                                          \
        uint2 w0v; w0v.x = pk2(e00, e01); w0v.y = pk2(e02, e03);               \
        uint2 w1v; w1v.x = pk2(e10, e11); w1v.y = pk2(e12, e13);               \
        *reinterpret_cast<uint2*>(&Pl[PM][(TT)*2048 + w*512 + lt*8 + (lg&1)*4]) = w0v; \
        *reinterpret_cast<uint2*>(&Pl[PM][(TT)*2048 + w*512 + (lt+32)*8 + (lg&1)*4]) = w1v; \
    }

// PV: consume tile (P bank PB, slot TT, V buf VB); vf reads -> lgkm(0) ->
// stage tile STJ into the freed V buf (STJ%3==VB) -> rescale -> lazy-pa MFMA.
#define PVSTEP(PB, TT, VB, STJ, DOSTAGE)                                       \
    {                                                                          \
        bf16x8_t vf[4];                                                        \
        _Pragma("unroll") for (int dt = 0; dt < 4; ++dt)                       \
            vf[dt] = load8(&Vl[VB][vread + dt * 512]);                         \
        asm volatile("s_waitcnt lgkmcnt(0)" ::: "memory");                     \
        if (DOSTAGE) {                                                         \
            const ushort_t* vsT = vsrc + (STJ) * 32;                           \
            _Pragma("unroll") for (int h = 0; h < 4; ++h)                      \
                GLL16(vsT + (size_t)h * 16 * N_, &Vl[VB][ds * 2048 + h * 512]); \
        }                                                                      \
        uint4 fv = *reinterpret_cast<const uint4*>(&flagl[PB][(TT) * 4]);      \
        if ((int)__builtin_amdgcn_readfirstlane(fv.x)) {                       \
            float fq = fl[PB][(TT) * 64 + lr];                                 \
            _Pragma("unroll") for (int dt = 0; dt < 4; ++dt) acc[dt][0] *= fq; \
        }                                                                      \
        if ((int)__builtin_amdgcn_readfirstlane(fv.y)) {                       \
            float fq = fl[PB][(TT) * 64 + 16 + lr];                            \
            _Pragma("unroll") for (int dt = 0; dt < 4; ++dt) acc[dt][1] *= fq; \
        }                                                                      \
        if ((int)__builtin_amdgcn_readfirstlane(fv.z)) {                       \
            float fq = fl[PB][(TT) * 64 + 32 + lr];                            \
            _Pragma("unroll") for (int dt = 0; dt < 4; ++dt) acc[dt][2] *= fq; \
        }                                                                      \
        if ((int)__builtin_amdgcn_readfirstlane(fv.w)) {                       \
            float fq = fl[PB][(TT) * 64 + 48 + lr];                            \
            _Pragma("unroll") for (int dt = 0; dt < 4; ++dt) acc[dt][3] *= fq; \
        }                                                                      \
        __builtin_amdgcn_s_setprio(1);                                         \
        _Pragma("unroll") for (int qt = 0; qt < 4; ++qt) {                     \
            bf16x8_t pa = load8(&Pl[PB][(TT) * 2048 + qt * 512 + l * 8]);      \
            _Pragma("unroll") for (int dt = 0; dt < 4; ++dt)                   \
                acc[dt][qt] = __builtin_amdgcn_mfma_f32_16x16x32_bf16(         \
                    vf[dt], pa, acc[dt][qt], 0, 0, 0);                         \
        }                                                                      \
        __builtin_amdgcn_s_setprio(0);                                         \
    }

    for (int p = 0; p < NP_; ++p) {
        int pb = p % 3;
        if (w < 4) {
            // stage K for period p+2
            if (p + 2 < NP_) {
                int pn = pb + 2; if (pn >= 3) pn -= 3;
                GLL16(ksrc + (size_t)(2 * p + 4) * 32 * NQK_, &Kl3[pn][w * 512]);
                GLL16(ksrc + (size_t)(2 * p + 5) * 32 * NQK_, &Kl3[pn][2048 + w * 512]);
            }
            const ushort_t* kbp = &Kl3[pb][0];
            // tile 2p
            bf16x8_t kf00, kf01, kf10, kf11;
            { int o = (lr << 7) + (lg << 4);              kf00 = load8(kbp + ((o ^ maskk) >> 1)); }
            { int o = (lr << 7) + 64 + (lg << 4);         kf01 = load8(kbp + ((o ^ maskk) >> 1)); }
            { int o = ((16 + lr) << 7) + (lg << 4);       kf10 = load8(kbp + ((o ^ maskk) >> 1)); }
            { int o = ((16 + lr) << 7) + 64 + (lg << 4);  kf11 = load8(kbp + ((o ^ maskk) >> 1)); }
            f32x4_t s00 = {0.f,0.f,0.f,0.f}, s01 = {0.f,0.f,0.f,0.f};
            s00 = __builtin_amdgcn_mfma_f32_16x16x32_bf16(kf00, qf0, s00, 0,0,0);
            s00 = __builtin_amdgcn_mfma_f32_16x16x32_bf16(kf01, qf1, s00, 0,0,0);
            s01 = __builtin_amdgcn_mfma_f32_16x16x32_bf16(kf10, qf0, s01, 0,0,0);
            s01 = __builtin_amdgcn_mfma_f32_16x16x32_bf16(kf11, qf1, s01, 0,0,0);
            // tile 2p+1
            const ushort_t* kbq = kbp + 2048;
            bf16x8_t kg00, kg01, kg10, kg11;
            { int o = (lr << 7) + (lg << 4);              kg00 = load8(kbq + ((o ^ maskk) >> 1)); }
            { int o = (lr << 7) + 64 + (lg << 4);         kg01 = load8(kbq + ((o ^ maskk) >> 1)); }
            { int o = ((16 + lr) << 7) + (lg << 4);       kg10 = load8(kbq + ((o ^ maskk) >> 1)); }
            { int o = ((16 + lr) << 7) + 64 + (lg << 4);  kg11 = load8(kbq + ((o ^ maskk) >> 1)); }
            f32x4_t s10 = {0.f,0.f,0.f,0.f}, s11 = {0.f,0.f,0.f,0.f};
            s10 = __builtin_amdgcn_mfma_f32_16x16x32_bf16(kg00, qf0, s10, 0,0,0);
            s10 = __builtin_amdgcn_mfma_f32_16x16x32_bf16(kg01, qf1, s10, 0,0,0);
            s11 = __builtin_amdgcn_mfma_f32_16x16x32_bf16(kg10, qf0, s11, 0,0,0);
            s11 = __builtin_amdgcn_mfma_f32_16x16x32_bf16(kg11, qf1, s11, 0,0,0);
            // softmax 2p (while 2p+1's MFMAs retire), then 2p+1
            int bank = p & 1;
            SOFTMAX_WRITE(s00, s01, bank, 0)
            SOFTMAX_WRITE(s10, s11, bank, 1)
            asm volatile("s_waitcnt vmcnt(2) lgkmcnt(0)" ::: "memory");
        } else {
            if (p >= 1) {
                int pbk = (p - 1) & 1;
                int j0 = 2 * p - 2, j1 = 2 * p - 1;
                PVSTEP(pbk, 0, j0 % 3, j0 + 3, (j0 + 3 < NT_))
                PVSTEP(pbk, 1, j1 % 3, j1 + 3, (j1 + 3 < NT_))
            }
            // period 0: nothing to consume; prologue staged V(0..2).
            asm volatile("s_waitcnt vmcnt(4)" ::: "memory");
        }
        asm volatile("" ::: "memory");
        __builtin_amdgcn_s_barrier();
        asm volatile("" ::: "memory");
    }

    // tail A: S reduces group-partial ssum, publishes invl;
    //         PV drains the last V stage (tile 127).
    if (w < 4) {
        ssum += __shfl_xor(ssum, 16);
        ssum += __shfl_xor(ssum, 32);
        if (lg == 0) invl[w * 16 + lr] = 1.0f / ssum;
        asm volatile("s_waitcnt lgkmcnt(0)" ::: "memory");
    } else {
        asm volatile("s_waitcnt vmcnt(0)" ::: "memory");
    }
    asm volatile("" ::: "memory");
    __builtin_amdgcn_s_barrier();
    asm volatile("" ::: "memory");

    // tail B: PV consumes tiles 126 (buf 126%3=0), 127 (buf 127%3=1); bank 1.
    if (w >= 4) {
        PVSTEP(1, 0, 0, 0, false)
        PVSTEP(1, 1, 1, 0, false)
        asm volatile("s_waitcnt lgkmcnt(0)" ::: "memory");

        // epilogue: coalesced out = gamma*acc/l + feat (D[d][q])
        float g = gamma[0];
        float iq0 = invl[lr], iq1 = invl[16 + lr], iq2 = invl[32 + lr], iq3 = invl[48 + lr];
        #pragma unroll
        for (int dt = 0; dt < 4; ++dt) {
            #pragma unroll
            for (int r = 0; r < 4; ++r) {
                size_t row = ((size_t)b * C_ + ds * 64 + dt * 16 + lg * 4 + r) * N_;
                size_t i0r = row + i0;
                { size_t idx = i0r + lr;      out[idx] = g * acc[dt][0][r] * iq0 + feat[idx]; }
                { size_t idx = i0r + 16 + lr; out[idx] = g * acc[dt][1][r] * iq1 + feat[idx]; }
                { size_t idx = i0r + 32 + lr; out[idx] = g * acc[dt][2][r] * iq2 + feat[idx]; }
                { size_t idx = i0r + 48 + lr; out[idx] = g * acc[dt][3][r] * iq3 + feat[idx]; }
            }
        }
    }
#undef PVSTEP
#undef SOFTMAX_WRITE
}

// ---------------------------------------------------------------- launch
extern "C" void kernel_launch(void* const* d_in, const int* in_sizes, int n_in,
                              void* d_out, int out_size, void* d_ws, size_t ws_size,
                              hipStream_t stream) {
    const float* feat  = (const float*)d_in[0];
    const float* w1    = (const float*)d_in[1];
    const float* b1    = (const float*)d_in[2];
    const float* w2    = (const float*)d_in[3];
    const float* b2    = (const float*)d_in[4];
    const float* w3    = (const float*)d_in[5];
    const float* b3    = (const float*)d_in[6];
    const float* gamma = (const float*)d_in[7];
    float* out = (float*)d_out;

    char* ws = (char*)d_ws;
    ushort_t* Xt      = (ushort_t*)(ws);
    ushort_t* Wb      = (ushort_t*)(ws + 16777216);
    float*    biasAll = (float*)   (ws + 17432576);
    ushort_t* QKp     = (ushort_t*)(ws + 17435136);
    ushort_t* Vp      = (ushort_t*)(ws + 21629440);
    if (ws_size < 38406656) return;

    hipLaunchKernelGGL(transpose_cast_x, dim3(64, 8, 5), dim3(256), 0, stream,
                       feat, Xt, w1, b1, w2, b2, w3, b3, Wb, biasAll);
    hipLaunchKernelGGL(gemm_qkv_kernel, dim3(32, 20), dim3(256), 0, stream,
                       Xt, Wb, biasAll, QKp, Vp);
    hipLaunchKernelGGL(attn_kernel, dim3(256), dim3(768), 0, stream,
                       QKp, Vp, feat, gamma, out);
}